// Round 14
// baseline (128.475 us; speedup 1.0000x reference)
//
#include <hip/hip_runtime.h>

// VectorQuantizer on MI355X (gfx950) — E-RESIDENT MFMA argmin (barrier-free
// code scan) + fused quantized write; f64 exact refine patches near-ties.
// R14: grid=256 (1 block/CU), 512 thr, LDS 160 KiB: full f16 hi/lo codebook
// resident (staged once), X tile staged per 128-pt group into a 32 KiB region
// that is aliased for merge scratch after the A-fragment hoist.  The 512-code
// scan is straight-line ds_read+MFMA with NO barriers and NO global traffic.
//
// Distance core: s = ||e||^2 - 2 x.e.  E pre-scaled by 2048, f16 hi/lo split,
// PRE-SWIZZLED in ws so global_load_lds (linear dest, per-lane source!) +
// XOR-swizzled ds_read line up.  X split into f16 hi/lo of (-2x).  3-term
// MFMA (xh.eh + xh.el + xl.eh).  C-init = (||e||^2+256)*2048; packed key
// ((uint)acc << 9) | idx -> u32-min argmin, first-min tie-break.  Near-ties
// (gap < 21/2048) re-solved in f64 by vq_refine (patches idx AND quantized
// rows).  Loss/hist pre-refine (error << tolerances); Sum(xnorm) carried in
// registers per staging wave (no per-point storage).

typedef __attribute__((ext_vector_type(8))) _Float16 f16x8;
typedef __attribute__((ext_vector_type(4))) float f32x4;
typedef unsigned int uint;
typedef unsigned short ushort;

namespace {
constexpr int kC = 64, kH = 64, kW = 64;
constexpr int kK = 512, kD = 64;
constexpr int kHW = kH * kW;                  // 4096
constexpr int kCHW = kC * kHW;                // 262144
constexpr int kN = 32 * kHW;                  // 131072
constexpr int kQElems = 32 * kC * kHW;        // 8388608
constexpr uint kGapFP = 21u;                  // 0.0103 in 1/2048 units
}

__device__ __forceinline__ ushort hb(_Float16 h) { return __builtin_bit_cast(ushort, h); }
__device__ __forceinline__ uint umin(uint a, uint b) { return a < b ? a : b; }
__device__ __forceinline__ uint umax(uint a, uint b) { return a > b ? a : b; }

__device__ __forceinline__ void gld16(const void* g, void* l) {
  __builtin_amdgcn_global_load_lds(
      (const __attribute__((address_space(1))) uint*)g,
      (__attribute__((address_space(3))) uint*)l, 16, 0, 0);
}

// ---- kernel 0: E -> pre-swizzled f16 hi/lo (x2048) + embT + enorm + zeros ----
__global__ __launch_bounds__(64) void vq_prep(const float* __restrict__ emb,
                                              ushort* __restrict__ embPh,
                                              ushort* __restrict__ embPl,
                                              float* __restrict__ embT,
                                              float* __restrict__ enorm,
                                              uint* __restrict__ counts,
                                              uint* __restrict__ flag_count) {
  const int k = blockIdx.x * 64 + threadIdx.x;
  const float4* __restrict__ ep4 = (const float4*)(emb + k * kD);
  float ev[kD];
  uint uh[32], ul[32];
  float s = 0.f;
#pragma unroll
  for (int j = 0; j < kD / 4; ++j) {
    const float4 v = ep4[j];
    ev[4 * j] = v.x; ev[4 * j + 1] = v.y; ev[4 * j + 2] = v.z; ev[4 * j + 3] = v.w;
    s = fmaf(v.x, v.x, s); s = fmaf(v.y, v.y, s);
    s = fmaf(v.z, v.z, s); s = fmaf(v.w, v.w, s);
#pragma unroll
    for (int t = 0; t < 2; ++t) {
      const float e0 = ev[4 * j + 2 * t] * 2048.f;
      const float e1 = ev[4 * j + 2 * t + 1] * 2048.f;
      const _Float16 h0 = (_Float16)e0, h1 = (_Float16)e1;
      const _Float16 l0 = (_Float16)(e0 - (float)h0);
      const _Float16 l1 = (_Float16)(e1 - (float)h1);
      uh[2 * j + t] = (uint)hb(h0) | ((uint)hb(h1) << 16);
      ul[2 * j + t] = (uint)hb(l0) | ((uint)hb(l1) << 16);
    }
  }
  // pre-swizzled store: embP[k*128B + (cc^(k&7))*16B] = linear chunk cc
  uint4* __restrict__ ph4 = (uint4*)embPh;
  uint4* __restrict__ pl4 = (uint4*)embPl;
#pragma unroll
  for (int cc = 0; cc < 8; ++cc) {
    const int dst = k * 8 + (cc ^ (k & 7));
    ph4[dst] = uint4{uh[4 * cc], uh[4 * cc + 1], uh[4 * cc + 2], uh[4 * cc + 3]};
    pl4[dst] = uint4{ul[4 * cc], ul[4 * cc + 1], ul[4 * cc + 2], ul[4 * cc + 3]};
  }
#pragma unroll
  for (int c = 0; c < kD; ++c) embT[c * kK + k] = ev[c];
  enorm[k] = s;
  counts[k] = 0u;
  if (k == 0) *flag_count = 0u;
}

// ---- kernel 1: E-resident MFMA argmin + flags + hist + loss + QUANT WRITE ----
// Grid 256, block 512 thr = 8 waves.  Per block: 512 points (4 groups x 128).
// Scan wave (pw=wv>>2 in {0,1}, cw=wv&3): 64 pts x 128 codes, barrier-free.
// Staging wave (ph=wv>>2, cs=wv&3): 64 pts x 16 dims.
// C/D: col=lane&15 (code), row=(lane>>4)*4+reg (point).
__global__ __launch_bounds__(512, 2) void vq_assign(
    const float* __restrict__ in, const ushort* __restrict__ embPh,
    const ushort* __restrict__ embPl, const float* __restrict__ embT,
    const float* __restrict__ enorm, float* __restrict__ idx_out,
    float* __restrict__ outq, uint* __restrict__ counts,
    float* __restrict__ partial, uint* __restrict__ flag_count,
    uint* __restrict__ flags, uint flag_cap) {
  __shared__ __align__(16) char lds[163840];
  ushort* __restrict__ Eh = (ushort*)lds;              // 64 KiB resident E hi
  ushort* __restrict__ El = (ushort*)(lds + 65536);    // 64 KiB resident E lo
  char* __restrict__ xbh = lds + 131072;               // 16 KiB X hi (f16 -2x)
  char* __restrict__ xbl = lds + 147456;               // 16 KiB X lo
  // aliased into the X region AFTER the A-hoist barrier:
  uint* __restrict__ mm1 = (uint*)(lds + 131072);      // [4][128]
  uint* __restrict__ mm2 = (uint*)(lds + 133120);      // [4][128]
  uint* __restrict__ fidx = (uint*)(lds + 135168);     // [128]
  float* __restrict__ xnsum = (float*)(lds + 135680);  // [8]
  float* __restrict__ ssum = (float*)(lds + 135712);   // [1]

  const int tid = threadIdx.x;
  const int lane = tid & 63;
  const int wv = __builtin_amdgcn_readfirstlane(tid >> 6);
  const int ph = wv >> 2;    // staging: point-half   | scan: pw (same bits)
  const int cs = wv & 3;     // staging: dim-quarter  | scan: cw code-quarter
  const int c = lane & 15;   // tile col (code)
  const int g = lane >> 4;   // k-chunk group 0..3

  const int blk = blockIdx.x;
  const int bb = blk >> 3;                  // batch (8 blocks per batch)
  const int hwB = (blk & 7) << 9;           // 512 consecutive hw points

  // ---- stage resident E once (pre-swizzled per-lane source -> linear dest)
#pragma unroll
  for (int i = 0; i < 8; ++i) {
    const int off = wv * 1024 + i * 8192;   // covers 64 KiB across 8 waves
    gld16((const char*)embPh + off + lane * 16, (char*)Eh + off);
    gld16((const char*)embPl + off + lane * 16, (char*)El + off);
  }

  // scaled+biased C-init per lane: this wave's 8 code-tiles (cw quarter)
  float en_pre[8];
#pragma unroll
  for (int ct = 0; ct < 8; ++ct)
    en_pre[ct] = (enorm[cs * 128 + ct * 16 + c] + 256.f) * 2048.f;

#pragma unroll 1
  for (int grp = 0; grp < 4; ++grp) {
    const int hw0 = hwB + (grp << 7);       // 128 pts this group
    const float* __restrict__ xp = in + (size_t)bb * kCHW + hw0 + ph * 64;

    // ---- stage X (hi/lo of -2x) + xnorm partial over this wave's 16 dims
    float xn = 0.f;
    {
      const int p = lane;
      uint uh[8], ul[8];
#pragma unroll
      for (int j = 0; j < 8; ++j) {
        const float f0 = xp[(size_t)(cs * 16 + 2 * j) * kHW + p];
        const float f1 = xp[(size_t)(cs * 16 + 2 * j + 1) * kHW + p];
        xn = fmaf(f0, f0, xn);
        xn = fmaf(f1, f1, xn);
        const float m0 = -2.f * f0, m1f = -2.f * f1;
        const _Float16 h0 = (_Float16)m0, h1 = (_Float16)m1f;
        const _Float16 l0 = (_Float16)(m0 - (float)h0);
        const _Float16 l1 = (_Float16)(m1f - (float)h1);
        uh[j] = (uint)hb(h0) | ((uint)hb(h1) << 16);
        ul[j] = (uint)hb(l0) | ((uint)hb(l1) << 16);
      }
      const int row = ph * 64 + p;
      const int swz = (row & 7) << 4;
      const int o0 = (row * 128 + cs * 32) ^ swz;
      const int o1 = (row * 128 + cs * 32 + 16) ^ swz;
      *(uint4*)(xbh + o0) = uint4{uh[0], uh[1], uh[2], uh[3]};
      *(uint4*)(xbh + o1) = uint4{uh[4], uh[5], uh[6], uh[7]};
      *(uint4*)(xbl + o0) = uint4{ul[0], ul[1], ul[2], ul[3]};
      *(uint4*)(xbl + o1) = uint4{ul[4], ul[5], ul[6], ul[7]};
    }
    __syncthreads();   // (1) X staged (+ resident E landed on grp 0)

    // ---- hoist ALL A-fragments (hi+lo): 16 f16x8 = 64 VGPR
    f16x8 ah[4][2], al[4][2];
#pragma unroll
    for (int rt = 0; rt < 4; ++rt)
#pragma unroll
      for (int s = 0; s < 2; ++s) {
        const int row = ph * 64 + rt * 16 + c;
        const int off = (row * 128 + g * 16 + s * 64) ^ ((row & 7) << 4);
        ah[rt][s] = *(const f16x8*)(xbh + off);
        al[rt][s] = *(const f16x8*)(xbl + off);
      }
    __syncthreads();   // (2) xb region free -> alias scratch

    // wave xnorm partial -> xnsum[wv]
    {
      float xw = xn;
#pragma unroll
      for (int off = 32; off > 0; off >>= 1) xw += __shfl_down(xw, off, 64);
      if (lane == 0) xnsum[wv] = xw;
    }

    // ---- barrier-free scan: this wave's 128 codes (cw quarter) x 64 pts
    uint m1[16], m2[16];
#pragma unroll
    for (int i = 0; i < 16; ++i) { m1[i] = 0xFFFFFFFFu; m2[i] = 0xFFFFFFFFu; }

#pragma unroll
    for (int ct = 0; ct < 8; ++ct) {
      const int k = cs * 128 + ct * 16 + c;       // global code row
      const int swb = (k & 7) << 4;
      const int ob0 = (k * 128 + g * 16) ^ swb;
      const int ob1 = (k * 128 + g * 16 + 64) ^ swb;
      const f16x8 bh0 = *(const f16x8*)((const char*)Eh + ob0);
      const f16x8 bh1 = *(const f16x8*)((const char*)Eh + ob1);
      const f16x8 bl0 = *(const f16x8*)((const char*)El + ob0);
      const f16x8 bl1 = *(const f16x8*)((const char*)El + ob1);
      const float en = en_pre[ct];
      const uint kor = (uint)k;
#pragma unroll
      for (int rt = 0; rt < 4; ++rt) {
        f32x4 acc = {en, en, en, en};
        acc = __builtin_amdgcn_mfma_f32_16x16x32_f16(ah[rt][0], bh0, acc, 0, 0, 0);
        acc = __builtin_amdgcn_mfma_f32_16x16x32_f16(ah[rt][1], bh1, acc, 0, 0, 0);
        acc = __builtin_amdgcn_mfma_f32_16x16x32_f16(ah[rt][0], bl0, acc, 0, 0, 0);
        acc = __builtin_amdgcn_mfma_f32_16x16x32_f16(ah[rt][1], bl1, acc, 0, 0, 0);
        acc = __builtin_amdgcn_mfma_f32_16x16x32_f16(al[rt][0], bh0, acc, 0, 0, 0);
        acc = __builtin_amdgcn_mfma_f32_16x16x32_f16(al[rt][1], bh1, acc, 0, 0, 0);
#pragma unroll
        for (int r = 0; r < 4; ++r) {
          const uint u = ((uint)acc[r] << 9) | kor;   // fixed-point pack
          const int i = rt * 4 + r;
          const uint t = umax(m1[i], u);
          m1[i] = umin(m1[i], u);
          m2[i] = umin(m2[i], t);
        }
      }
    }

    // ---- cross-col butterfly (16 c-lanes per point) ----
#pragma unroll
    for (int i = 0; i < 16; ++i) {
      uint a1 = m1[i], a2 = m2[i];
#pragma unroll
      for (int off = 1; off < 16; off <<= 1) {
        const uint o1 = __shfl_xor(a1, off, 64);
        const uint o2 = __shfl_xor(a2, off, 64);
        const uint t = umax(a1, o1);
        a1 = umin(a1, o1);
        a2 = umin(umin(a2, o2), t);
      }
      m1[i] = a1; m2[i] = a2;
    }
    if (c == 0) {
#pragma unroll
      for (int i = 0; i < 16; ++i) {
        const int p = ph * 64 + (i >> 2) * 16 + g * 4 + (i & 3);
        mm1[cs * 128 + p] = m1[i];
        mm2[cs * 128 + p] = m2[i];
      }
    }
    __syncthreads();   // (3) all mm + xnsum ready

    // ---- cross-wave (4 cw) merge + idx/flags/hist/loss ----
    float s0 = 0.f;
    if (tid < 128) {
      uint a1 = mm1[tid], a2 = mm2[tid];
#pragma unroll
      for (int s = 1; s < 4; ++s) {
        const uint u1 = mm1[s * 128 + tid], u2 = mm2[s * 128 + tid];
        const uint t = umax(a1, u1);
        a1 = umin(a1, u1);
        a2 = umin(umin(a2, u2), t);
      }
      const uint bidx = a1 & 511u;
      fidx[tid] = bidx;
      const int n = bb * kHW + hw0 + tid;
      idx_out[n] = (float)bidx;
      if (((a2 >> 9) - (a1 >> 9)) < kGapFP) {   // near-tie -> exact recheck
        const uint slot = atomicAdd(flag_count, 1u);
        if (slot < flag_cap) flags[slot] = (uint)n;
      }
      atomicAdd(&counts[bidx], 1u);

      float d2s = fmaf((float)(a1 >> 9), 1.f / 2048.f, -256.f);
#pragma unroll
      for (int off = 32; off > 0; off >>= 1) d2s += __shfl_down(d2s, off, 64);
      if (tid == 64) *ssum = d2s;
      s0 = d2s;
    }
    __syncthreads();   // (4) fidx/ssum ready
    if (tid == 0) {
      float xs = (xnsum[0] + xnsum[1]) + (xnsum[2] + xnsum[3]) +
                 (xnsum[4] + xnsum[5]) + (xnsum[6] + xnsum[7]);
      partial[blk * 4 + grp] = s0 + *ssum + xs;
    }

    // ---- fused quantized write: 128 pts x 64 c, coalesced NCHW stores ----
    {
      const int ch = tid >> 3;          // channel 0..63
      const int wq = tid & 7;           // 16-pt chunk 0..7
      const float* __restrict__ tr = embT + ch * kK;
      float* __restrict__ oq =
          outq + (size_t)bb * kCHW + (size_t)ch * kHW + hw0 + wq * 16;
#pragma unroll
      for (int i = 0; i < 4; ++i) {
        const int p0 = wq * 16 + i * 4;
        float4 v;
        v.x = tr[fidx[p0 + 0]];
        v.y = tr[fidx[p0 + 1]];
        v.z = tr[fidx[p0 + 2]];
        v.w = tr[fidx[p0 + 3]];
        *(float4*)(oq + i * 4) = v;
      }
    }
    __syncthreads();   // (5) alias region reusable next group
  }
}

// ---- kernel 1b: exact f64 re-argmin, ONE WAVE per flagged point; patches
// both idx_out and the quantized output row.
__global__ __launch_bounds__(256) void vq_refine(const float* __restrict__ in,
                                                 const float* __restrict__ emb,
                                                 const uint* __restrict__ flag_count,
                                                 const uint* __restrict__ flags,
                                                 uint flag_cap,
                                                 float* __restrict__ idx_out,
                                                 float* __restrict__ outq) {
  uint cnt = *flag_count;
  if (cnt > flag_cap) cnt = flag_cap;
  const int lane = threadIdx.x & 63;
  const uint wave_id = blockIdx.x * 4u + (threadIdx.x >> 6);
  const uint wave_stride = gridDim.x * 4u;

  for (uint i = wave_id; i < cnt; i += wave_stride) {
    const int n = (int)flags[i];          // wave-uniform
    const int b = n >> 12;
    const int hw = n & 4095;
    const float* __restrict__ xp = in + (size_t)b * kCHW + hw;

    float xr[kD];
#pragma unroll
    for (int d = 0; d < kD; ++d) xr[d] = xp[(size_t)d * kHW];

    double best = 1e300;
    int bidx = 0;
#pragma unroll 1
    for (int kk = 0; kk < 8; ++kk) {
      const int k = lane * 8 + kk;
      const float4* __restrict__ ep4 = (const float4*)(emb + k * kD);
      double s0 = 0.0, s1 = 0.0;
#pragma unroll
      for (int j = 0; j < kD / 4; ++j) {
        const float4 e = ep4[j];
        const double d0 = (double)xr[4 * j + 0] - (double)e.x;
        const double d1 = (double)xr[4 * j + 1] - (double)e.y;
        const double d2 = (double)xr[4 * j + 2] - (double)e.z;
        const double d3 = (double)xr[4 * j + 3] - (double)e.w;
        s0 = fma(d0, d0, s0);
        s1 = fma(d1, d1, s1);
        s0 = fma(d2, d2, s0);
        s1 = fma(d3, d3, s1);
      }
      const double s = s0 + s1;
      if (s < best) { best = s; bidx = k; }  // strict < == first-min in-lane
    }
#pragma unroll
    for (int off = 32; off > 0; off >>= 1) {
      const double ob = __shfl_xor(best, off, 64);
      const int oi = __shfl_xor(bidx, off, 64);
      if (ob < best || (ob == best && oi < bidx)) { best = ob; bidx = oi; }
    }
    if (lane == 0) idx_out[n] = (float)bidx;
    // patch quantized row: lane = channel
    outq[(size_t)b * kCHW + (size_t)lane * kHW + hw] = emb[bidx * kD + lane];
  }
}

// ---- kernel 2: scalars (loss, perplexity, usage) -----------------------------
__global__ __launch_bounds__(512) void vq_finalize(const float* __restrict__ weight,
                                                   const uint* __restrict__ counts,
                                                   const float* __restrict__ partial,
                                                   float* __restrict__ out_scalars) {
  __shared__ float red[512];
  const int t = threadIdx.x;

  const float avg = (float)counts[t] / (float)kN;
  red[t] = avg * logf(avg + 1e-10f);
  __syncthreads();
#pragma unroll
  for (int off = 256; off > 0; off >>= 1) {
    if (t < off) red[t] += red[t + off];
    __syncthreads();
  }
  const float perp = expf(-red[0]);
  __syncthreads();

  // 1024 loss partials, fixed order -> deterministic
  red[t] = partial[t] + partial[t + 512];
  __syncthreads();
#pragma unroll
  for (int off = 256; off > 0; off >>= 1) {
    if (t < off) red[t] += red[t + off];
    __syncthreads();
  }
  const float loss = red[0] / (float)((long long)kN * (long long)kD);
  __syncthreads();

  red[t] = (weight[t] >= 0.01f) ? 1.f : 0.f;
  __syncthreads();
#pragma unroll
  for (int off = 256; off > 0; off >>= 1) {
    if (t < off) red[t] += red[t + off];
    __syncthreads();
  }
  if (t == 0) {
    out_scalars[0] = loss;
    out_scalars[1] = perp;
    out_scalars[2] = red[0];
  }
}

extern "C" void kernel_launch(void* const* d_in, const int* in_sizes, int n_in,
                              void* d_out, int out_size, void* d_ws, size_t ws_size,
                              hipStream_t stream) {
  const float* in = (const float*)d_in[0];
  const float* emb = (const float*)d_in[1];
  const float* weight = (const float*)d_in[2];
  float* out = (float*)d_out;

  // workspace layout (4 B units)
  float* ws_f = (float*)d_ws;
  uint* ws_u = (uint*)d_ws;
  ushort* embPh = (ushort*)d_ws;            // 64 KiB  -> u32 [0, 16384)
  ushort* embPl = embPh + kK * kD;          // 64 KiB  -> u32 [16384, 32768)
  float* embT = ws_f + 32768;               // 128 KiB -> [32768, 65536)
  float* enorm = ws_f + 65536;              // [512]
  uint* counts = ws_u + 66048;              // [512]
  float* partial = ws_f + 66560;            // [1024]
  uint* flag_count = ws_u + 67584;          // [1]
  uint* flags = ws_u + 67585;               // [flag_cap]
  const size_t ws_elems = ws_size / 4;
  const uint flag_cap =
      (ws_elems > 67585)
          ? (uint)((ws_elems - 67585 < (size_t)kN) ? ws_elems - 67585 : (size_t)kN)
          : 0u;

  float* outq = out;                    // [8388608]
  float* out_scalars = out + kQElems;   // [3]
  float* idx_out = out + kQElems + 3;   // [131072]

  vq_prep<<<8, 64, 0, stream>>>(emb, embPh, embPl, embT, enorm, counts, flag_count);
  vq_assign<<<256, 512, 0, stream>>>(in, embPh, embPl, embT, enorm, idx_out,
                                     outq, counts, partial, flag_count, flags,
                                     flag_cap);
  vq_refine<<<256, 256, 0, stream>>>(in, emb, flag_count, flags, flag_cap,
                                     idx_out, outq);
  vq_finalize<<<1, 512, 0, stream>>>(weight, counts, partial, out_scalars);
}

// Round 15
// 90.226 us; speedup vs baseline: 1.4239x; 1.4239x over previous
//
#include <hip/hip_runtime.h>

// VectorQuantizer on MI355X (gfx950) — async-pipelined MFMA argmin (counted
// vmcnt, raw s_barrier) with fused quantized write; f64 refine patches ties.
// R15 = r9 structure (512 thr, 8 waves, 128 pts, 8x64-code dbuf chunks, no
// A-hoist, 2 blocks/CU) + T3/T4 pipeline:
//   * SELF-STAGED E: wave (ph,cs) gld16-stages exactly the 16 rows it reads
//     (ph-siblings duplicate identical bytes — benign); chunk-landed ordering
//     is per-wave counted vmcnt(4), never vmcnt(0) in the loop.
//   * step = {issue next chunk; vmcnt(4); sched_barrier; compute;
//     lgkmcnt(0); raw s_barrier} — prefetch stays in flight across barriers.
//
// Distance core: s = ||e||^2 - 2 x.e.  E pre-scaled by 2048, f16 hi/lo split,
// PRE-SWIZZLED in ws (per-lane gld16 source, linear LDS dest).  X = f16 hi/lo
// of (-2x).  3-term MFMA (xh.eh + xh.el + xl.eh).  C-init = (||e||^2+256)*2048;
// packed key ((uint)acc << 9) | idx -> u32-min argmin, first-min tie-break.
// Near-ties (gap < 21/2048) re-solved in f64 by vq_refine (patches idx AND
// quantized rows).  Loss/hist pre-refine (error << tolerances).

typedef __attribute__((ext_vector_type(8))) _Float16 f16x8;
typedef __attribute__((ext_vector_type(4))) float f32x4;
typedef unsigned int uint;
typedef unsigned short ushort;

namespace {
constexpr int kC = 64, kH = 64, kW = 64;
constexpr int kK = 512, kD = 64;
constexpr int kHW = kH * kW;                  // 4096
constexpr int kCHW = kC * kHW;                // 262144
constexpr int kN = 32 * kHW;                  // 131072
constexpr int kQElems = 32 * kC * kHW;        // 8388608
constexpr uint kGapFP = 21u;                  // 0.0103 in 1/2048 units
}

__device__ __forceinline__ ushort hb(_Float16 h) { return __builtin_bit_cast(ushort, h); }
__device__ __forceinline__ uint umin(uint a, uint b) { return a < b ? a : b; }
__device__ __forceinline__ uint umax(uint a, uint b) { return a > b ? a : b; }

__device__ __forceinline__ void gld16(const void* g, void* l) {
  __builtin_amdgcn_global_load_lds(
      (const __attribute__((address_space(1))) uint*)g,
      (__attribute__((address_space(3))) uint*)l, 16, 0, 0);
}

// ---- kernel 0: E -> pre-swizzled f16 hi/lo (x2048) + embT + enorm + zeros ----
__global__ __launch_bounds__(64) void vq_prep(const float* __restrict__ emb,
                                              ushort* __restrict__ embPh,
                                              ushort* __restrict__ embPl,
                                              float* __restrict__ embT,
                                              float* __restrict__ enorm,
                                              uint* __restrict__ counts,
                                              uint* __restrict__ flag_count) {
  const int k = blockIdx.x * 64 + threadIdx.x;
  const float4* __restrict__ ep4 = (const float4*)(emb + k * kD);
  float ev[kD];
  uint uh[32], ul[32];
  float s = 0.f;
#pragma unroll
  for (int j = 0; j < kD / 4; ++j) {
    const float4 v = ep4[j];
    ev[4 * j] = v.x; ev[4 * j + 1] = v.y; ev[4 * j + 2] = v.z; ev[4 * j + 3] = v.w;
    s = fmaf(v.x, v.x, s); s = fmaf(v.y, v.y, s);
    s = fmaf(v.z, v.z, s); s = fmaf(v.w, v.w, s);
#pragma unroll
    for (int t = 0; t < 2; ++t) {
      const float e0 = ev[4 * j + 2 * t] * 2048.f;
      const float e1 = ev[4 * j + 2 * t + 1] * 2048.f;
      const _Float16 h0 = (_Float16)e0, h1 = (_Float16)e1;
      const _Float16 l0 = (_Float16)(e0 - (float)h0);
      const _Float16 l1 = (_Float16)(e1 - (float)h1);
      uh[2 * j + t] = (uint)hb(h0) | ((uint)hb(h1) << 16);
      ul[2 * j + t] = (uint)hb(l0) | ((uint)hb(l1) << 16);
    }
  }
  // pre-swizzled store: embP[k*128B + (cc^(k&7))*16B] = linear chunk cc
  uint4* __restrict__ ph4 = (uint4*)embPh;
  uint4* __restrict__ pl4 = (uint4*)embPl;
#pragma unroll
  for (int cc = 0; cc < 8; ++cc) {
    const int dst = k * 8 + (cc ^ (k & 7));
    ph4[dst] = uint4{uh[4 * cc], uh[4 * cc + 1], uh[4 * cc + 2], uh[4 * cc + 3]};
    pl4[dst] = uint4{ul[4 * cc], ul[4 * cc + 1], ul[4 * cc + 2], ul[4 * cc + 3]};
  }
#pragma unroll
  for (int c = 0; c < kD; ++c) embT[c * kK + k] = ev[c];
  enorm[k] = s;
  counts[k] = 0u;
  if (k == 0) *flag_count = 0u;
}

// ---- kernel 1: MFMA argmin + flags + hist + loss + QUANTIZED WRITE -----------
// Block = 512 thr = 8 waves = 128 points x all 512 codes in 8 dbuf-staged
// 64-code chunks.  Wave (ph=wv>>2, cs=wv&3).  Wave stages ITS OWN 16 rows.
// C/D: col=lane&15 (code), row=(lane>>4)*4+reg (point).
__global__ __launch_bounds__(512, 4) void vq_assign(
    const float* __restrict__ in, const ushort* __restrict__ embPh,
    const ushort* __restrict__ embPl, const float* __restrict__ embT,
    const float* __restrict__ enorm, float* __restrict__ idx_out,
    float* __restrict__ outq, uint* __restrict__ counts,
    float* __restrict__ partial, uint* __restrict__ flag_count,
    uint* __restrict__ flags, uint flag_cap) {
  __shared__ __align__(16) ushort xbh[128 * 64];  // 16 KiB X hi (f16 of -2x)
  __shared__ __align__(16) ushort xbl[128 * 64];  // 16 KiB X lo
  __shared__ __align__(16) ushort ebh[2][4096];   // 16 KiB E hi dbuf (64 codes)
  __shared__ __align__(16) ushort ebl[2][4096];   // 16 KiB E lo dbuf
  __shared__ uint mm1[4][128], mm2[4][128];       // 4 KiB merge
  __shared__ float xnp[4][128];                   // 2 KiB xnorm partials
  __shared__ uint hist[512];                      // 2 KiB block histogram
  __shared__ uint fidx[128];                      // pre-refine indices

  const int tid = threadIdx.x;
  const int lane = tid & 63;
  const int wv = __builtin_amdgcn_readfirstlane(tid >> 6);
  const int ph = wv >> 2;    // point-half
  const int cs = wv & 3;     // code-sub (16 codes per 64-code chunk)
  const int c = lane & 15;   // tile col (code)
  const int g = lane >> 4;   // k-chunk group 0..3

  const int blk = blockIdx.x;
  const int bb = blk >> 5;                  // batch
  const int hw0 = (blk & 31) << 7;          // 128 contiguous hw points
  const float* __restrict__ xp = in + (size_t)bb * kCHW + hw0 + ph * 64;

  hist[tid] = 0u;

  // SELF-STAGE: wave (ph,cs) stages rows [cs*16, cs*16+16) of chunk st —
  // exactly the rows it reads.  ph-siblings write identical bytes (benign).
  // 4 gld16/wave/step -> counted vmcnt(4) orders own reads without drains.
  auto stageE = [&](int buf, int st) {
    const size_t src = (size_t)st * 8192 + cs * 2048;
    const int dst = cs * 2048;
#pragma unroll
    for (int i = 0; i < 2; ++i) {
      gld16((const char*)embPh + src + i * 1024 + lane * 16,
            (char*)&ebh[buf][0] + dst + i * 1024);
      gld16((const char*)embPl + src + i * 1024 + lane * 16,
            (char*)&ebl[buf][0] + dst + i * 1024);
    }
  };
  stageE(0, 0);   // prologue prefetch, flies under X staging

  // scaled+biased C-init per lane for the 8 chunks
  float en_pre[8];
#pragma unroll
  for (int st = 0; st < 8; ++st)
    en_pre[st] = (enorm[st * 64 + cs * 16 + c] + 256.f) * 2048.f;

  // ---- stage X (hi/lo of -2x) + xnorm partial over this wave's 16 dims ----
  {
    const int p = lane;
    uint uh[8], ul[8];
    float xn = 0.f;
#pragma unroll
    for (int j = 0; j < 8; ++j) {
      const float f0 = xp[(size_t)(cs * 16 + 2 * j) * kHW + p];
      const float f1 = xp[(size_t)(cs * 16 + 2 * j + 1) * kHW + p];
      xn = fmaf(f0, f0, xn);
      xn = fmaf(f1, f1, xn);
      const float m0 = -2.f * f0, m1f = -2.f * f1;
      const _Float16 h0 = (_Float16)m0, h1 = (_Float16)m1f;
      const _Float16 l0 = (_Float16)(m0 - (float)h0);
      const _Float16 l1 = (_Float16)(m1f - (float)h1);
      uh[j] = (uint)hb(h0) | ((uint)hb(h1) << 16);
      ul[j] = (uint)hb(l0) | ((uint)hb(l1) << 16);
    }
    const int row = ph * 64 + p;
    const int swz = (row & 7) << 4;
    const int o0 = (row * 128 + cs * 32) ^ swz;
    const int o1 = (row * 128 + cs * 32 + 16) ^ swz;
    *(uint4*)((char*)xbh + o0) = uint4{uh[0], uh[1], uh[2], uh[3]};
    *(uint4*)((char*)xbh + o1) = uint4{uh[4], uh[5], uh[6], uh[7]};
    *(uint4*)((char*)xbl + o0) = uint4{ul[0], ul[1], ul[2], ul[3]};
    *(uint4*)((char*)xbl + o1) = uint4{ul[4], ul[5], ul[6], ul[7]};
    xnp[cs][row] = xn;
  }
  __syncthreads();   // full drain ONCE: X staged + chunk 0 landed

  uint m1[16], m2[16];
#pragma unroll
  for (int i = 0; i < 16; ++i) { m1[i] = 0xFFFFFFFFu; m2[i] = 0xFFFFFFFFu; }

#pragma unroll
  for (int st = 0; st < 8; ++st) {
    if (st < 7) stageE((st & 1) ^ 1, st + 1);   // prefetch stays in flight

    // counted wait: my own chunk-st loads landed (4 newest = chunk st+1)
    if (st < 7) {
      asm volatile("s_waitcnt vmcnt(4)" ::: "memory");
    } else {
      asm volatile("s_waitcnt vmcnt(0)" ::: "memory");
    }
    __builtin_amdgcn_sched_barrier(0);

    // B-frags: this wave's 16-code slice of the chunk (self-staged)
    const int rowb = cs * 16 + c;
    const int swb = (rowb & 7) << 4;
    const int ob0 = (rowb * 128 + g * 16) ^ swb;
    const int ob1 = (rowb * 128 + g * 16 + 64) ^ swb;
    const int bsel = st & 1;
    const f16x8 bh0 = *(const f16x8*)((const char*)&ebh[bsel][0] + ob0);
    const f16x8 bh1 = *(const f16x8*)((const char*)&ebh[bsel][0] + ob1);
    const f16x8 bl0 = *(const f16x8*)((const char*)&ebl[bsel][0] + ob0);
    const f16x8 bl1 = *(const f16x8*)((const char*)&ebl[bsel][0] + ob1);
    const float en = en_pre[st];
    const uint kor = (uint)(st * 64 + cs * 16 + c);
    __builtin_amdgcn_s_setprio(1);
#pragma unroll
    for (int rt = 0; rt < 4; ++rt) {
      f16x8 ah[2], al[2];
#pragma unroll
      for (int s = 0; s < 2; ++s) {
        const int row = ph * 64 + rt * 16 + c;
        const int off = (row * 128 + g * 16 + s * 64) ^ ((row & 7) << 4);
        ah[s] = *(const f16x8*)((const char*)xbh + off);
        al[s] = *(const f16x8*)((const char*)xbl + off);
      }
      f32x4 acc = {en, en, en, en};
      acc = __builtin_amdgcn_mfma_f32_16x16x32_f16(ah[0], bh0, acc, 0, 0, 0);
      acc = __builtin_amdgcn_mfma_f32_16x16x32_f16(ah[1], bh1, acc, 0, 0, 0);
      acc = __builtin_amdgcn_mfma_f32_16x16x32_f16(ah[0], bl0, acc, 0, 0, 0);
      acc = __builtin_amdgcn_mfma_f32_16x16x32_f16(ah[1], bl1, acc, 0, 0, 0);
      acc = __builtin_amdgcn_mfma_f32_16x16x32_f16(al[0], bh0, acc, 0, 0, 0);
      acc = __builtin_amdgcn_mfma_f32_16x16x32_f16(al[1], bh1, acc, 0, 0, 0);
#pragma unroll
      for (int r = 0; r < 4; ++r) {
        const uint u = ((uint)acc[r] << 9) | kor;   // fixed-point pack
        const int i = rt * 4 + r;
        const uint t = umax(m1[i], u);
        m1[i] = umin(m1[i], u);
        m2[i] = umin(m2[i], t);
      }
    }
    __builtin_amdgcn_s_setprio(0);

    // step-end rendezvous WITHOUT vmcnt drain: my ds_reads done (lgkm only),
    // then raw barrier bounds wave drift to 1 step (WAR on dbuf regions).
    asm volatile("s_waitcnt lgkmcnt(0)" ::: "memory");
    __builtin_amdgcn_sched_barrier(0);
    __builtin_amdgcn_s_barrier();
  }

  // ---- cross-col butterfly (16 c-lanes per point) ----
#pragma unroll
  for (int i = 0; i < 16; ++i) {
    uint a1 = m1[i], a2 = m2[i];
#pragma unroll
    for (int off = 1; off < 16; off <<= 1) {
      const uint o1 = __shfl_xor(a1, off, 64);
      const uint o2 = __shfl_xor(a2, off, 64);
      const uint t = umax(a1, o1);
      a1 = umin(a1, o1);
      a2 = umin(umin(a2, o2), t);
    }
    m1[i] = a1; m2[i] = a2;
  }

  if (c == 0) {
#pragma unroll
    for (int i = 0; i < 16; ++i) {
      const int p = ph * 64 + (i >> 2) * 16 + g * 4 + (i & 3);
      mm1[cs][p] = m1[i];
      mm2[cs][p] = m2[i];
    }
  }
  __syncthreads();

  // ---- cross-wave merge + idx/flags/hist/loss ----
  if (tid < 128) {
    uint a1 = mm1[0][tid], a2 = mm2[0][tid];
#pragma unroll
    for (int s = 1; s < 4; ++s) {
      const uint u1 = mm1[s][tid], u2 = mm2[s][tid];
      const uint t = umax(a1, u1);
      a1 = umin(a1, u1);
      a2 = umin(umin(a2, u2), t);
    }
    const uint bidx = a1 & 511u;
    fidx[tid] = bidx;
    idx_out[blk * 128 + tid] = (float)bidx;
    if (((a2 >> 9) - (a1 >> 9)) < kGapFP) {   // near-tie -> exact recheck
      const uint slot = atomicAdd(flag_count, 1u);
      if (slot < flag_cap) flags[slot] = (uint)(blk * 128 + tid);
    }
    atomicAdd(&hist[bidx], 1u);

    const float xnorm = (xnp[0][tid] + xnp[1][tid]) + (xnp[2][tid] + xnp[3][tid]);
    float d2 = fmaf((float)(a1 >> 9), 1.f / 2048.f, -256.f) + xnorm;
#pragma unroll
    for (int off = 32; off > 0; off >>= 1) d2 += __shfl_down(d2, off, 64);
    if ((tid & 63) == 0) partial[blk * 2 + (tid >> 6)] = d2;
  }
  __syncthreads();
  if (hist[tid]) atomicAdd(&counts[tid], hist[tid]);

  // ---- fused quantized write: 128 pts x 64 c, coalesced NCHW stores ----
  {
    const int ch = tid >> 3;          // channel 0..63
    const int wq = tid & 7;           // 16-pt chunk 0..7
    const float* __restrict__ tr = embT + ch * kK;
    float* __restrict__ oq = outq + (size_t)bb * kCHW + (size_t)ch * kHW + hw0 + wq * 16;
#pragma unroll
    for (int i = 0; i < 4; ++i) {
      const int p0 = wq * 16 + i * 4;
      float4 v;
      v.x = tr[fidx[p0 + 0]];
      v.y = tr[fidx[p0 + 1]];
      v.z = tr[fidx[p0 + 2]];
      v.w = tr[fidx[p0 + 3]];
      *(float4*)(oq + i * 4) = v;
    }
  }
}

// ---- kernel 1b: exact f64 re-argmin, ONE WAVE per flagged point; patches
// both idx_out and the quantized output row.
__global__ __launch_bounds__(256) void vq_refine(const float* __restrict__ in,
                                                 const float* __restrict__ emb,
                                                 const uint* __restrict__ flag_count,
                                                 const uint* __restrict__ flags,
                                                 uint flag_cap,
                                                 float* __restrict__ idx_out,
                                                 float* __restrict__ outq) {
  uint cnt = *flag_count;
  if (cnt > flag_cap) cnt = flag_cap;
  const int lane = threadIdx.x & 63;
  const uint wave_id = blockIdx.x * 4u + (threadIdx.x >> 6);
  const uint wave_stride = gridDim.x * 4u;

  for (uint i = wave_id; i < cnt; i += wave_stride) {
    const int n = (int)flags[i];          // wave-uniform
    const int b = n >> 12;
    const int hw = n & 4095;
    const float* __restrict__ xp = in + (size_t)b * kCHW + hw;

    float xr[kD];
#pragma unroll
    for (int d = 0; d < kD; ++d) xr[d] = xp[(size_t)d * kHW];

    double best = 1e300;
    int bidx = 0;
#pragma unroll 1
    for (int kk = 0; kk < 8; ++kk) {
      const int k = lane * 8 + kk;
      const float4* __restrict__ ep4 = (const float4*)(emb + k * kD);
      double s0 = 0.0, s1 = 0.0;
#pragma unroll
      for (int j = 0; j < kD / 4; ++j) {
        const float4 e = ep4[j];
        const double d0 = (double)xr[4 * j + 0] - (double)e.x;
        const double d1 = (double)xr[4 * j + 1] - (double)e.y;
        const double d2 = (double)xr[4 * j + 2] - (double)e.z;
        const double d3 = (double)xr[4 * j + 3] - (double)e.w;
        s0 = fma(d0, d0, s0);
        s1 = fma(d1, d1, s1);
        s0 = fma(d2, d2, s0);
        s1 = fma(d3, d3, s1);
      }
      const double s = s0 + s1;
      if (s < best) { best = s; bidx = k; }  // strict < == first-min in-lane
    }
#pragma unroll
    for (int off = 32; off > 0; off >>= 1) {
      const double ob = __shfl_xor(best, off, 64);
      const int oi = __shfl_xor(bidx, off, 64);
      if (ob < best || (ob == best && oi < bidx)) { best = ob; bidx = oi; }
    }
    if (lane == 0) idx_out[n] = (float)bidx;
    // patch quantized row: lane = channel
    outq[(size_t)b * kCHW + (size_t)lane * kHW + hw] = emb[bidx * kD + lane];
  }
}

// ---- kernel 2: scalars (loss, perplexity, usage) -----------------------------
__global__ __launch_bounds__(512) void vq_finalize(const float* __restrict__ weight,
                                                   const uint* __restrict__ counts,
                                                   const float* __restrict__ partial,
                                                   float* __restrict__ out_scalars) {
  __shared__ float red[512];
  const int t = threadIdx.x;

  const float avg = (float)counts[t] / (float)kN;
  red[t] = avg * logf(avg + 1e-10f);
  __syncthreads();
#pragma unroll
  for (int off = 256; off > 0; off >>= 1) {
    if (t < off) red[t] += red[t + off];
    __syncthreads();
  }
  const float perp = expf(-red[0]);
  __syncthreads();

  // 2048 loss partials, fixed order -> deterministic
  red[t] = (partial[t] + partial[t + 512]) + (partial[t + 1024] + partial[t + 1536]);
  __syncthreads();
#pragma unroll
  for (int off = 256; off > 0; off >>= 1) {
    if (t < off) red[t] += red[t + off];
    __syncthreads();
  }
  const float loss = red[0] / (float)((long long)kN * (long long)kD);
  __syncthreads();

  red[t] = (weight[t] >= 0.01f) ? 1.f : 0.f;
  __syncthreads();
#pragma unroll
  for (int off = 256; off > 0; off >>= 1) {
    if (t < off) red[t] += red[t + off];
    __syncthreads();
  }
  if (t == 0) {
    out_scalars[0] = loss;
    out_scalars[1] = perp;
    out_scalars[2] = red[0];
  }
}

extern "C" void kernel_launch(void* const* d_in, const int* in_sizes, int n_in,
                              void* d_out, int out_size, void* d_ws, size_t ws_size,
                              hipStream_t stream) {
  const float* in = (const float*)d_in[0];
  const float* emb = (const float*)d_in[1];
  const float* weight = (const float*)d_in[2];
  float* out = (float*)d_out;

  // workspace layout (4 B units)
  float* ws_f = (float*)d_ws;
  uint* ws_u = (uint*)d_ws;
  ushort* embPh = (ushort*)d_ws;            // 64 KiB  -> u32 [0, 16384)
  ushort* embPl = embPh + kK * kD;          // 64 KiB  -> u32 [16384, 32768)
  float* embT = ws_f + 32768;               // 128 KiB -> [32768, 65536)
  float* enorm = ws_f + 65536;              // [512]
  uint* counts = ws_u + 66048;              // [512]
  float* partial = ws_f + 66560;            // [2048]
  uint* flag_count = ws_u + 68608;          // [1]
  uint* flags = ws_u + 68609;               // [flag_cap]
  const size_t ws_elems = ws_size / 4;
  const uint flag_cap =
      (ws_elems > 68609)
          ? (uint)((ws_elems - 68609 < (size_t)kN) ? ws_elems - 68609 : (size_t)kN)
          : 0u;

  float* outq = out;                    // [8388608]
  float* out_scalars = out + kQElems;   // [3]
  float* idx_out = out + kQElems + 3;   // [131072]

  vq_prep<<<8, 64, 0, stream>>>(emb, embPh, embPl, embT, enorm, counts, flag_count);
  vq_assign<<<kN / 128, 512, 0, stream>>>(in, embPh, embPl, embT, enorm, idx_out,
                                          outq, counts, partial, flag_count, flags,
                                          flag_cap);
  vq_refine<<<256, 256, 0, stream>>>(in, emb, flag_count, flags, flag_cap,
                                     idx_out, outq);
  vq_finalize<<<1, 512, 0, stream>>>(weight, counts, partial, out_scalars);
}